// Round 7
// baseline (842.728 us; speedup 1.0000x reference)
//
#include <hip/hip_runtime.h>
#include <hip/hip_bf16.h>

// CxNNxNN attention. B=8, C=64, H=W=256, head=8, N=8.
// token n = (h&7)*8 + (w&7)  [64], feature d = (h>>3)*32 + (w>>3)  [1024].

typedef __attribute__((ext_vector_type(8))) short short8;  // 8 bf16 (4 VGPR)
typedef __attribute__((ext_vector_type(4))) float f4;      // MFMA acc
typedef __attribute__((ext_vector_type(16))) float f16v;   // s_load_dwordx16
typedef unsigned short u16;

#define PST 72  // bf16 plane row stride (ushorts); 144B rows, 16B-aligned frags

// ---------------- K1/K3: pointwise GEMM  out[oc] = sum_c w[oc,c] * in[c] ----
// R6 counters: VALUBusy 42% @ 70% occ -- stalled on lgkm: ds_read(x) mixed
// with ~768 narrow s_load_dwordx4 (weights) in the FMA stream share lgkmcnt.
// Fix: (1) x chunk (32 c) copied LDS->VGPR up front, drained once; (2) weights
// as wide 64B uniform vector loads (s_load_dwordx16), 64 FMAs cover per pair.
template <int OC>
__global__ __launch_bounds__(256) void k_pw(const float* in,
                                            const float* __restrict__ w,
                                            float* outp) {
  constexpr int PEROC = OC / 4;   // 48 (qkv) or 16 (proj)
  constexpr int NG = PEROC / 16;  // 3 or 1 groups of 16 oc
  __shared__ float xl[64][64];    // 16KB
  const int t = threadIdx.x;
  const int p = t & 63;
  const int qw = __builtin_amdgcn_readfirstlane(t >> 6);  // oc-quarter, SGPR
  const size_t pix0 = (size_t)blockIdx.x * 64;
  const int b = (int)(pix0 >> 16);
  const int hw0 = (int)(pix0 & 65535);
  const float* ib = in + (((size_t)b * 64) << 16) + hw0 + p;
#pragma unroll
  for (int r = 0; r < 16; ++r) {
    int c = r * 4 + (t >> 6);
    xl[c][p] = ib[(size_t)c << 16];  // wave: 256B coalesced
  }
  __syncthreads();
  float* ob = outp + (((size_t)b * OC) << 16) + hw0 + p;
#pragma unroll 1
  for (int g = 0; g < NG; ++g) {
    const float* wg = w + (qw * PEROC + g * 16) * 64;  // SGPR-uniform base
    float acc[16];
#pragma unroll
    for (int j = 0; j < 16; ++j) acc[j] = 0.f;
#pragma unroll 1
    for (int cc = 0; cc < 2; ++cc) {
      float xc[32];  // x chunk in VGPRs; lgkm drained once here
#pragma unroll
      for (int e = 0; e < 32; ++e) xc[e] = xl[cc * 32 + e][p];
#pragma unroll
      for (int j = 0; j < 16; ++j) {
        const f16v* wv = (const f16v*)(wg + j * 64 + cc * 32);  // 64B uniform
        f16v w0 = wv[0], w1 = wv[1];  // -> s_load_dwordx16 pair
#pragma unroll
        for (int e = 0; e < 16; ++e) {
          acc[j] = fmaf(w0[e], xc[e], acc[j]);
          acc[j] = fmaf(w1[e], xc[16 + e], acc[j]);
        }
      }
    }
#pragma unroll
    for (int j = 0; j < 16; ++j)
      ob[(size_t)(qw * PEROC + g * 16 + j) << 16] = acc[j];
  }
}

// ---------------- bf16 hi/lo helpers ----------------
__device__ __forceinline__ float tof(u16 u) {
  return __builtin_bit_cast(float, ((unsigned)u) << 16);
}
__device__ __forceinline__ void fsplit(float o, u16& h, u16& l) {
  unsigned u = __builtin_bit_cast(unsigned, o);
  h = (u16)(u >> 16);  // truncate; lo compensates
  float hf = __builtin_bit_cast(float, u & 0xffff0000u);
  l = (u16)(__builtin_bit_cast(unsigned, o - hf) >> 16);
}
// all MFMA operand frags: row = base+(lane&15), 8 ushorts at ko = 32*ks+8*(lane>>4)
__device__ __forceinline__ short8 ldfrag(const u16* p, int row, int ko) {
  return *(const short8*)&p[row * PST + ko];
}

// ---- depthwise 3x3 conv: one run = 8 tokens (n=nb..nb+7) at one feature dcol --
__device__ __forceinline__ void conv_run(const float* __restrict__ pl,
                                         const float* __restrict__ w9, int cd,
                                         int r, float o[8], int& nb,
                                         int& dcol) {
  int lr = r >> 5, w0 = r & 31;
  int h = cd * 16 + lr;
  float rv[3][10];
#pragma unroll
  for (int dy = 0; dy < 3; ++dy) {
    int hy = h + dy - 1;
    bool hv = (hy >= 0) && (hy < 256);
#pragma unroll
    for (int j = 0; j < 10; ++j) rv[dy][j] = 0.f;
    if (hv) {
      const float* rp = pl + hy * 256;
      const float4* rp4 = (const float4*)(rp + w0 * 8);
      float4 a = rp4[0], b4 = rp4[1];
      rv[dy][1] = a.x;  rv[dy][2] = a.y;  rv[dy][3] = a.z;  rv[dy][4] = a.w;
      rv[dy][5] = b4.x; rv[dy][6] = b4.y; rv[dy][7] = b4.z; rv[dy][8] = b4.w;
      rv[dy][0] = (w0 > 0) ? rp[w0 * 8 - 1] : 0.f;
      rv[dy][9] = (w0 < 31) ? rp[w0 * 8 + 8] : 0.f;
    }
  }
  nb = (lr & 7) * 8;
  dcol = ((lr >> 3) << 5) + w0;
#pragma unroll
  for (int i = 0; i < 8; ++i) {
    o[i] = fmaf(w9[0], rv[0][i], fmaf(w9[1], rv[0][i + 1], fmaf(w9[2], rv[0][i + 2],
            fmaf(w9[3], rv[1][i], fmaf(w9[4], rv[1][i + 1], fmaf(w9[5], rv[1][i + 2],
            fmaf(w9[6], rv[2][i], fmaf(w9[7], rv[2][i + 1], w9[8] * rv[2][i + 2]))))))));
  }
}

// stage Q/K chunk as hi/lo planes [64 n][PST d]  (scalar b16 writes, ~4-way ok)
__device__ __forceinline__ void stage_nk(const float* __restrict__ pl,
                                         const float* __restrict__ w9,
                                         u16* __restrict__ ph,
                                         u16* __restrict__ plo, int cd, int t) {
#pragma unroll
  for (int rr = 0; rr < 2; ++rr) {
    float o[8]; int nb, dcol;
    conv_run(pl, w9, cd, t + rr * 256, o, nb, dcol);
#pragma unroll
    for (int i = 0; i < 8; ++i) {
      u16 h, l;
      fsplit(o[i], h, l);
      ph[(nb + i) * PST + dcol] = h;
      plo[(nb + i) * PST + dcol] = l;
    }
  }
}

// stage V chunk TRANSPOSED [64 d][PST n]: 8 consecutive n -> packed b128 writes
__device__ __forceinline__ void stage_vt(const float* __restrict__ pl,
                                         const float* __restrict__ w9,
                                         u16* __restrict__ ph,
                                         u16* __restrict__ plo, int cd, int t) {
#pragma unroll
  for (int rr = 0; rr < 2; ++rr) {
    float o[8]; int nb, dcol;
    conv_run(pl, w9, cd, t + rr * 256, o, nb, dcol);
    short8 hv, lv;
#pragma unroll
    for (int i = 0; i < 8; ++i) {
      u16 h, l;
      fsplit(o[i], h, l);
      hv[i] = (short)h;
      lv[i] = (short)l;
    }
    *(short8*)&ph[dcol * PST + nb] = hv;
    *(short8*)&plo[dcol * PST + nb] = lv;
  }
}

// ---------------- K2: MFMA attention, conv fused in staging ----------------
// Per (b,ch): 16 chunks of d=64. QK^T: S(64x64) += Q_chunk . K_chunk^T via
// mfma_f32_16x16x32_bf16 with hi/lo split (3 products, ~fp32 accuracy).
// Norm rescale commutes: S = (q.k) * invq * invk * temp, applied pre-softmax.
__global__ __launch_bounds__(256) void k_attn(
    const float* __restrict__ qkv0, const float* __restrict__ wdw,
    const float* __restrict__ temperature, float* __restrict__ out) {
  __shared__ u16 SAh[64 * PST], SAl[64 * PST];  // Q planes, then P planes
  __shared__ u16 SBh[64 * PST], SBl[64 * PST];  // K planes, then V^T planes
  __shared__ float red[64 * 8];
  __shared__ float invn[128];

  const int t = threadIdx.x;
  const int b = blockIdx.x >> 6, ch = blockIdx.x & 63;
  const float* qpl = qkv0 + (((size_t)b * 192 + ch) << 16);
  const float* kpl = qkv0 + (((size_t)b * 192 + 64 + ch) << 16);
  const float* vpl = qkv0 + (((size_t)b * 192 + 128 + ch) << 16);
  float wq[9], wk[9], wv[9];
#pragma unroll
  for (int i = 0; i < 9; ++i) {
    wq[i] = wdw[ch * 9 + i];
    wk[i] = wdw[(64 + ch) * 9 + i];
    wv[i] = wdw[(128 + ch) * 9 + i];
  }
  const float tscale = temperature[ch >> 3];

  const int wid = t >> 6;        // wave 0..3: S rows 16*wid..+15
  const int g = (t >> 4) & 3;    // lane>>4 within wave
  const int r16 = t & 15;        // lane&15

  f4 acc[4];
#pragma unroll
  for (int cb = 0; cb < 4; ++cb)
#pragma unroll
    for (int e = 0; e < 4; ++e) acc[cb][e] = 0.f;
  float sqQ = 0.f, sqK = 0.f;

  for (int cd = 0; cd < 16; ++cd) {
    stage_nk(qpl, wq, SAh, SAl, cd, t);
    stage_nk(kpl, wk, SBh, SBl, cd, t);
    __syncthreads();
    {  // sumsq on reconstructed (hi+lo) values: row n=t>>2, 16 cols
      const int n = t >> 2, c0 = (t & 3) << 4;
#pragma unroll
      for (int h2 = 0; h2 < 2; ++h2) {
        short8 qh = *(const short8*)&SAh[n * PST + c0 + 8 * h2];
        short8 ql = *(const short8*)&SAl[n * PST + c0 + 8 * h2];
        short8 kh = *(const short8*)&SBh[n * PST + c0 + 8 * h2];
        short8 kl = *(const short8*)&SBl[n * PST + c0 + 8 * h2];
#pragma unroll
        for (int e = 0; e < 8; ++e) {
          float qv = tof((u16)qh[e]) + tof((u16)ql[e]);
          float kv = tof((u16)kh[e]) + tof((u16)kl[e]);
          sqQ = fmaf(qv, qv, sqQ);
          sqK = fmaf(kv, kv, sqK);
        }
      }
    }
#pragma unroll
    for (int ks = 0; ks < 2; ++ks) {
      const int ko = ks * 32 + g * 8;
      short8 ah = ldfrag(SAh, wid * 16 + r16, ko);
      short8 al = ldfrag(SAl, wid * 16 + r16, ko);
#pragma unroll
      for (int cb = 0; cb < 4; ++cb) {
        short8 bh = ldfrag(SBh, cb * 16 + r16, ko);
        short8 bl = ldfrag(SBl, cb * 16 + r16, ko);
        acc[cb] = __builtin_amdgcn_mfma_f32_16x16x32_bf16(ah, bh, acc[cb], 0, 0, 0);
        acc[cb] = __builtin_amdgcn_mfma_f32_16x16x32_bf16(ah, bl, acc[cb], 0, 0, 0);
        acc[cb] = __builtin_amdgcn_mfma_f32_16x16x32_bf16(al, bh, acc[cb], 0, 0, 0);
      }
    }
    __syncthreads();
  }

  // reduce sumsq -> 1/max(||.||, 1e-12)
  red[(t >> 2) * 8 + (t & 3)] = sqQ;
  red[(t >> 2) * 8 + 4 + (t & 3)] = sqK;
  __syncthreads();
  if (t < 128) {
    int n = t & 63;
    int o = (t >> 6) * 4;
    float s = red[n * 8 + o] + red[n * 8 + o + 1] + red[n * 8 + o + 2] +
              red[n * 8 + o + 3];
    invn[(t >> 6) * 64 + n] = 1.f / fmaxf(sqrtf(s), 1e-12f);
  }
  __syncthreads();

  // scale + softmax. C/D layout: row n = 16*wid+4*g+r, col m = 16*cb+r16.
  float iqv[4], ikv[4];
#pragma unroll
  for (int r = 0; r < 4; ++r) iqv[r] = invn[wid * 16 + g * 4 + r];
#pragma unroll
  for (int cb = 0; cb < 4; ++cb) ikv[cb] = invn[64 + cb * 16 + r16];
  float pr[4][4];  // [r][cb]
#pragma unroll
  for (int r = 0; r < 4; ++r) {
    float sv[4];
#pragma unroll
    for (int cb = 0; cb < 4; ++cb)
      sv[cb] = acc[cb][r] * iqv[r] * ikv[cb] * tscale;
    float mx = fmaxf(fmaxf(sv[0], sv[1]), fmaxf(sv[2], sv[3]));
#pragma unroll
    for (int off = 1; off < 16; off <<= 1) mx = fmaxf(mx, __shfl_xor(mx, off));
    float ss = 0.f;
#pragma unroll
    for (int cb = 0; cb < 4; ++cb) {
      sv[cb] = __expf(sv[cb] - mx);
      ss += sv[cb];
    }
#pragma unroll
    for (int off = 1; off < 16; off <<= 1) ss += __shfl_xor(ss, off);
    float rs = 1.f / ss;
#pragma unroll
    for (int cb = 0; cb < 4; ++cb) pr[r][cb] = sv[cb] * rs;
  }

  // restage P into SA planes [64 n][PST m] (Q fully consumed)
#pragma unroll
  for (int r = 0; r < 4; ++r)
#pragma unroll
    for (int cb = 0; cb < 4; ++cb) {
      u16 h, l;
      fsplit(pr[r][cb], h, l);
      int n = wid * 16 + g * 4 + r, m = cb * 16 + r16;
      SAh[n * PST + m] = h;
      SAl[n * PST + m] = l;
    }
  __syncthreads();

  // P A-frags fixed across chunks: row = 16*wid + r16, k = m
  short8 pah[2], pal[2];
#pragma unroll
  for (int ks = 0; ks < 2; ++ks) {
    pah[ks] = ldfrag(SAh, wid * 16 + r16, ks * 32 + g * 8);
    pal[ks] = ldfrag(SAl, wid * 16 + r16, ks * 32 + g * 8);
  }

  // PV: per chunk O(64n x 64d) = P(64x64) . V(64m x 64d); B from V^T planes
  size_t obase = ((size_t)b * 64 + ch) << 16;
  for (int cd = 0; cd < 16; ++cd) {
    stage_vt(vpl, wv, SBh, SBl, cd, t);
    __syncthreads();
    f4 po[4];
#pragma unroll
    for (int cb = 0; cb < 4; ++cb)
#pragma unroll
      for (int e = 0; e < 4; ++e) po[cb][e] = 0.f;
#pragma unroll
    for (int ks = 0; ks < 2; ++ks) {
      const int ko = ks * 32 + g * 8;
#pragma unroll
      for (int cb = 0; cb < 4; ++cb) {
        short8 bh = ldfrag(SBh, cb * 16 + r16, ko);
        short8 bl = ldfrag(SBl, cb * 16 + r16, ko);
        po[cb] = __builtin_amdgcn_mfma_f32_16x16x32_bf16(pah[ks], bh, po[cb], 0, 0, 0);
        po[cb] = __builtin_amdgcn_mfma_f32_16x16x32_bf16(pah[ks], bl, po[cb], 0, 0, 0);
        po[cb] = __builtin_amdgcn_mfma_f32_16x16x32_bf16(pal[ks], bh, po[cb], 0, 0, 0);
      }
    }
#pragma unroll
    for (int cb = 0; cb < 4; ++cb)
#pragma unroll
      for (int r = 0; r < 4; ++r) {
        int n = wid * 16 + g * 4 + r;
        int d = cd * 64 + cb * 16 + r16;
        int hh = ((d >> 5) << 3) + (n >> 3);
        int ww = ((d & 31) << 3) + (n & 7);
        out[obase + hh * 256 + ww] = po[cb][r];
      }
    __syncthreads();
  }
}

extern "C" void kernel_launch(void* const* d_in, const int* in_sizes, int n_in,
                              void* d_out, int out_size, void* d_ws,
                              size_t ws_size, hipStream_t stream) {
  const float* x = (const float*)d_in[0];
  const float* wqkv = (const float*)d_in[1];
  const float* wdw = (const float*)d_in[2];
  const float* wproj = (const float*)d_in[3];
  const float* temp = (const float*)d_in[4];
  float* out = (float*)d_out;
  float* qkv0 = (float*)d_ws;  // 8*192*65536*4 = 402,653,184 bytes

  k_pw<192><<<8192, 256, 0, stream>>>(x, wqkv, qkv0);
  k_attn<<<512, 256, 0, stream>>>(qkv0, wdw, temp, out);
  k_pw<64><<<8192, 256, 0, stream>>>(out, wproj, out);
}

// Round 8
// 405.346 us; speedup vs baseline: 2.0790x; 2.0790x over previous
//
#include <hip/hip_runtime.h>
#include <hip/hip_bf16.h>

// CxNNxNN attention. B=8, C=64, H=W=256, head=8, N=8.
// token n = (h&7)*8 + (w&7)  [64], feature d = (h>>3)*32 + (w>>3)  [1024].

typedef __attribute__((ext_vector_type(8))) short short8;  // 8 bf16 (4 VGPR)
typedef __attribute__((ext_vector_type(4))) float f4;      // MFMA acc
typedef unsigned short u16;

#define PST 72  // bf16 plane row stride (ushorts); 144B rows: bank rotates 4/row -> <=2-way

// ---------------- bf16 hi/lo helpers ----------------
__device__ __forceinline__ float tof(u16 u) {
  return __builtin_bit_cast(float, ((unsigned)u) << 16);
}
__device__ __forceinline__ void fsplit(float o, u16& h, u16& l) {
  unsigned u = __builtin_bit_cast(unsigned, o);
  h = (u16)(u >> 16);  // truncate; lo compensates
  float hf = __builtin_bit_cast(float, u & 0xffff0000u);
  l = (u16)(__builtin_bit_cast(unsigned, o - hf) >> 16);
}
// MFMA operand frags from [row][k] planes: row = base+(lane&15),
// 8 ushorts at ko = 32*ks + 8*((lane>>4)&3)
__device__ __forceinline__ short8 ldfrag(const u16* p, int row, int ko) {
  return *(const short8*)&p[row * PST + ko];
}

// ---------------- K1/K3: pointwise GEMM on MFMA ----------------
// out[oc,pix] = sum_c w[oc,c] x[c,pix].  M=OC, K=64, N=64 px per block.
// R6 scalar version: 42% VALU @ lgkm-stalled (SMEM weights + LDS share
// lgkmcnt); R7 vector-scalar-load attempt: compiler put weights in VGPRs,
// 4x VALU issue. Fix: MFMA w/ hi-lo bf16 split -> compute 16us chip-wide,
// purely memory-bound. Weights: per-wave global dwordx4 loads, split
// in-register (VMEM/vmcnt path -- no SMEM in hot loop). x: bf16 planes
// XT[px][c] in LDS (18KB). In-place proj safe: x reads land in LDS before
// barrier; blocks own disjoint pixels.
template <int OC>
__global__ __launch_bounds__(256) void k_pwm(const float* in,
                                             const float* __restrict__ w,
                                             float* outp) {
  constexpr int MT = OC / 64;  // M-tiles per wave: 3 (qkv) or 1 (proj)
  __shared__ u16 XTh[64 * PST], XTl[64 * PST];
  const int t = threadIdx.x;
  const int px = t & 63, cg = t >> 6;
  const size_t pix0 = (size_t)blockIdx.x * 64;
  const int b = (int)(pix0 >> 16);
  const int hw0 = (int)(pix0 & 65535);
  const float* ib = in + (((size_t)b * 64) << 16) + hw0 + px;
  // stage x^T bf16 hi/lo planes: wave cg covers c = 16cg..16cg+15
#pragma unroll
  for (int j = 0; j < 2; ++j) {
    short8 hv, lv;
#pragma unroll
    for (int e = 0; e < 8; ++e) {
      int c = cg * 16 + j * 8 + e;
      float xv = ib[(size_t)c << 16];  // lanes: 256B coalesced
      u16 h, l;
      fsplit(xv, h, l);
      hv[e] = (short)h;
      lv[e] = (short)l;
    }
    *(short8*)&XTh[px * PST + cg * 16 + j * 8] = hv;
    *(short8*)&XTl[px * PST + cg * 16 + j * 8] = lv;
  }
  __syncthreads();
  const int wid = t >> 6, g = (t >> 4) & 3, r16 = t & 15;
  const int oc0 = wid * 16 * MT;
  // A-frags: w[oc][c] rows via dwordx4 pairs, hi/lo split in-register
  short8 ah[MT][2], al[MT][2];
#pragma unroll
  for (int m = 0; m < MT; ++m)
#pragma unroll
    for (int ks = 0; ks < 2; ++ks) {
      const float* wr = w + (oc0 + m * 16 + r16) * 64 + ks * 32 + g * 8;
      float4 a0 = *(const float4*)wr;
      float4 a1 = *(const float4*)(wr + 4);
      float av[8] = {a0.x, a0.y, a0.z, a0.w, a1.x, a1.y, a1.z, a1.w};
      short8 h8, l8;
#pragma unroll
      for (int e = 0; e < 8; ++e) {
        u16 h, l;
        fsplit(av[e], h, l);
        h8[e] = (short)h;
        l8[e] = (short)l;
      }
      ah[m][ks] = h8;
      al[m][ks] = l8;
    }
  float* ob = outp + (((size_t)b * OC) << 16) + hw0;
#pragma unroll
  for (int nt = 0; nt < 4; ++nt) {  // N-tiles of 16 px
    short8 bh[2], bl[2];
#pragma unroll
    for (int ks = 0; ks < 2; ++ks) {
      bh[ks] = ldfrag(XTh, nt * 16 + r16, ks * 32 + g * 8);
      bl[ks] = ldfrag(XTl, nt * 16 + r16, ks * 32 + g * 8);
    }
    f4 acc[MT];
#pragma unroll
    for (int m = 0; m < MT; ++m)
#pragma unroll
      for (int e = 0; e < 4; ++e) acc[m][e] = 0.f;
#pragma unroll
    for (int m = 0; m < MT; ++m)
#pragma unroll
      for (int ks = 0; ks < 2; ++ks) {
        acc[m] = __builtin_amdgcn_mfma_f32_16x16x32_bf16(ah[m][ks], bh[ks], acc[m], 0, 0, 0);
        acc[m] = __builtin_amdgcn_mfma_f32_16x16x32_bf16(ah[m][ks], bl[ks], acc[m], 0, 0, 0);
        acc[m] = __builtin_amdgcn_mfma_f32_16x16x32_bf16(al[m][ks], bh[ks], acc[m], 0, 0, 0);
      }
    // C: row(oc) = oc0+16m+4g+e, col(px) = 16nt+r16 -> 64B runs per 16 lanes
#pragma unroll
    for (int m = 0; m < MT; ++m)
#pragma unroll
      for (int e = 0; e < 4; ++e) {
        int oc = oc0 + m * 16 + g * 4 + e;
        ob[((size_t)oc << 16) + nt * 16 + r16] = acc[m][e];
      }
  }
}

// ---- depthwise 3x3 conv: one run = 8 tokens (n=nb..nb+7) at one feature dcol --
__device__ __forceinline__ void conv_run(const float* __restrict__ pl,
                                         const float* __restrict__ w9, int cd,
                                         int r, float o[8], int& nb,
                                         int& dcol) {
  int lr = r >> 5, w0 = r & 31;
  int h = cd * 16 + lr;
  float rv[3][10];
#pragma unroll
  for (int dy = 0; dy < 3; ++dy) {
    int hy = h + dy - 1;
    bool hv = (hy >= 0) && (hy < 256);
#pragma unroll
    for (int j = 0; j < 10; ++j) rv[dy][j] = 0.f;
    if (hv) {
      const float* rp = pl + hy * 256;
      const float4* rp4 = (const float4*)(rp + w0 * 8);
      float4 a = rp4[0], b4 = rp4[1];
      rv[dy][1] = a.x;  rv[dy][2] = a.y;  rv[dy][3] = a.z;  rv[dy][4] = a.w;
      rv[dy][5] = b4.x; rv[dy][6] = b4.y; rv[dy][7] = b4.z; rv[dy][8] = b4.w;
      rv[dy][0] = (w0 > 0) ? rp[w0 * 8 - 1] : 0.f;
      rv[dy][9] = (w0 < 31) ? rp[w0 * 8 + 8] : 0.f;
    }
  }
  nb = (lr & 7) * 8;
  dcol = ((lr >> 3) << 5) + w0;
#pragma unroll
  for (int i = 0; i < 8; ++i) {
    o[i] = fmaf(w9[0], rv[0][i], fmaf(w9[1], rv[0][i + 1], fmaf(w9[2], rv[0][i + 2],
            fmaf(w9[3], rv[1][i], fmaf(w9[4], rv[1][i + 1], fmaf(w9[5], rv[1][i + 2],
            fmaf(w9[6], rv[2][i], fmaf(w9[7], rv[2][i + 1], w9[8] * rv[2][i + 2]))))))));
  }
}

// stage Q/K chunk as hi/lo planes [64 n][PST d]  (scalar b16 writes, ~4-way ok)
__device__ __forceinline__ void stage_nk(const float* __restrict__ pl,
                                         const float* __restrict__ w9,
                                         u16* __restrict__ ph,
                                         u16* __restrict__ plo, int cd, int t) {
#pragma unroll
  for (int rr = 0; rr < 2; ++rr) {
    float o[8]; int nb, dcol;
    conv_run(pl, w9, cd, t + rr * 256, o, nb, dcol);
#pragma unroll
    for (int i = 0; i < 8; ++i) {
      u16 h, l;
      fsplit(o[i], h, l);
      ph[(nb + i) * PST + dcol] = h;
      plo[(nb + i) * PST + dcol] = l;
    }
  }
}

// stage V chunk TRANSPOSED [64 d][PST n]: 8 consecutive n -> packed b128 writes
__device__ __forceinline__ void stage_vt(const float* __restrict__ pl,
                                         const float* __restrict__ w9,
                                         u16* __restrict__ ph,
                                         u16* __restrict__ plo, int cd, int t) {
#pragma unroll
  for (int rr = 0; rr < 2; ++rr) {
    float o[8]; int nb, dcol;
    conv_run(pl, w9, cd, t + rr * 256, o, nb, dcol);
    short8 hv, lv;
#pragma unroll
    for (int i = 0; i < 8; ++i) {
      u16 h, l;
      fsplit(o[i], h, l);
      hv[i] = (short)h;
      lv[i] = (short)l;
    }
    *(short8*)&ph[dcol * PST + nb] = hv;
    *(short8*)&plo[dcol * PST + nb] = lv;
  }
}

// ---------------- K2: MFMA attention, conv fused in staging ----------------
// Per (b,ch): 16 chunks of d=64. QK^T: S(64x64) += Q_chunk . K_chunk^T via
// mfma_f32_16x16x32_bf16 with hi/lo split (3 products, ~fp32 accuracy).
// Norm rescale commutes: S = (q.k) * invq * invk * temp, applied pre-softmax.
__global__ __launch_bounds__(256) void k_attn(
    const float* __restrict__ qkv0, const float* __restrict__ wdw,
    const float* __restrict__ temperature, float* __restrict__ out) {
  __shared__ u16 SAh[64 * PST], SAl[64 * PST];  // Q planes, then P planes
  __shared__ u16 SBh[64 * PST], SBl[64 * PST];  // K planes, then V^T planes
  __shared__ float red[64 * 8];
  __shared__ float invn[128];

  const int t = threadIdx.x;
  const int b = blockIdx.x >> 6, ch = blockIdx.x & 63;
  const float* qpl = qkv0 + (((size_t)b * 192 + ch) << 16);
  const float* kpl = qkv0 + (((size_t)b * 192 + 64 + ch) << 16);
  const float* vpl = qkv0 + (((size_t)b * 192 + 128 + ch) << 16);
  float wq[9], wk[9], wv[9];
#pragma unroll
  for (int i = 0; i < 9; ++i) {
    wq[i] = wdw[ch * 9 + i];
    wk[i] = wdw[(64 + ch) * 9 + i];
    wv[i] = wdw[(128 + ch) * 9 + i];
  }
  const float tscale = temperature[ch >> 3];

  const int wid = t >> 6;        // wave 0..3: S rows 16*wid..+15
  const int g = (t >> 4) & 3;    // lane>>4 within wave
  const int r16 = t & 15;        // lane&15

  f4 acc[4];
#pragma unroll
  for (int cb = 0; cb < 4; ++cb)
#pragma unroll
    for (int e = 0; e < 4; ++e) acc[cb][e] = 0.f;
  float sqQ = 0.f, sqK = 0.f;

  for (int cd = 0; cd < 16; ++cd) {
    stage_nk(qpl, wq, SAh, SAl, cd, t);
    stage_nk(kpl, wk, SBh, SBl, cd, t);
    __syncthreads();
    {  // sumsq on reconstructed (hi+lo) values: row n=t>>2, 16 cols
      const int n = t >> 2, c0 = (t & 3) << 4;
#pragma unroll
      for (int h2 = 0; h2 < 2; ++h2) {
        short8 qh = *(const short8*)&SAh[n * PST + c0 + 8 * h2];
        short8 ql = *(const short8*)&SAl[n * PST + c0 + 8 * h2];
        short8 kh = *(const short8*)&SBh[n * PST + c0 + 8 * h2];
        short8 kl = *(const short8*)&SBl[n * PST + c0 + 8 * h2];
#pragma unroll
        for (int e = 0; e < 8; ++e) {
          float qv = tof((u16)qh[e]) + tof((u16)ql[e]);
          float kv = tof((u16)kh[e]) + tof((u16)kl[e]);
          sqQ = fmaf(qv, qv, sqQ);
          sqK = fmaf(kv, kv, sqK);
        }
      }
    }
#pragma unroll
    for (int ks = 0; ks < 2; ++ks) {
      const int ko = ks * 32 + g * 8;
      short8 ah = ldfrag(SAh, wid * 16 + r16, ko);
      short8 al = ldfrag(SAl, wid * 16 + r16, ko);
#pragma unroll
      for (int cb = 0; cb < 4; ++cb) {
        short8 bh = ldfrag(SBh, cb * 16 + r16, ko);
        short8 bl = ldfrag(SBl, cb * 16 + r16, ko);
        acc[cb] = __builtin_amdgcn_mfma_f32_16x16x32_bf16(ah, bh, acc[cb], 0, 0, 0);
        acc[cb] = __builtin_amdgcn_mfma_f32_16x16x32_bf16(ah, bl, acc[cb], 0, 0, 0);
        acc[cb] = __builtin_amdgcn_mfma_f32_16x16x32_bf16(al, bh, acc[cb], 0, 0, 0);
      }
    }
    __syncthreads();
  }

  // reduce sumsq -> 1/max(||.||, 1e-12)
  red[(t >> 2) * 8 + (t & 3)] = sqQ;
  red[(t >> 2) * 8 + 4 + (t & 3)] = sqK;
  __syncthreads();
  if (t < 128) {
    int n = t & 63;
    int o = (t >> 6) * 4;
    float s = red[n * 8 + o] + red[n * 8 + o + 1] + red[n * 8 + o + 2] +
              red[n * 8 + o + 3];
    invn[(t >> 6) * 64 + n] = 1.f / fmaxf(sqrtf(s), 1e-12f);
  }
  __syncthreads();

  // scale + softmax. C/D layout: row n = 16*wid+4*g+r, col m = 16*cb+r16.
  float iqv[4], ikv[4];
#pragma unroll
  for (int r = 0; r < 4; ++r) iqv[r] = invn[wid * 16 + g * 4 + r];
#pragma unroll
  for (int cb = 0; cb < 4; ++cb) ikv[cb] = invn[64 + cb * 16 + r16];
  float pr[4][4];  // [r][cb]
#pragma unroll
  for (int r = 0; r < 4; ++r) {
    float sv[4];
#pragma unroll
    for (int cb = 0; cb < 4; ++cb)
      sv[cb] = acc[cb][r] * iqv[r] * ikv[cb] * tscale;
    float mx = fmaxf(fmaxf(sv[0], sv[1]), fmaxf(sv[2], sv[3]));
#pragma unroll
    for (int off = 1; off < 16; off <<= 1) mx = fmaxf(mx, __shfl_xor(mx, off));
    float ss = 0.f;
#pragma unroll
    for (int cb = 0; cb < 4; ++cb) {
      sv[cb] = __expf(sv[cb] - mx);
      ss += sv[cb];
    }
#pragma unroll
    for (int off = 1; off < 16; off <<= 1) ss += __shfl_xor(ss, off);
    float rs = 1.f / ss;
#pragma unroll
    for (int cb = 0; cb < 4; ++cb) pr[r][cb] = sv[cb] * rs;
  }

  // restage P into SA planes [64 n][PST m] (Q fully consumed)
#pragma unroll
  for (int r = 0; r < 4; ++r)
#pragma unroll
    for (int cb = 0; cb < 4; ++cb) {
      u16 h, l;
      fsplit(pr[r][cb], h, l);
      int n = wid * 16 + g * 4 + r, m = cb * 16 + r16;
      SAh[n * PST + m] = h;
      SAl[n * PST + m] = l;
    }
  __syncthreads();

  // P A-frags fixed across chunks: row = 16*wid + r16, k = m
  short8 pah[2], pal[2];
#pragma unroll
  for (int ks = 0; ks < 2; ++ks) {
    pah[ks] = ldfrag(SAh, wid * 16 + r16, ks * 32 + g * 8);
    pal[ks] = ldfrag(SAl, wid * 16 + r16, ks * 32 + g * 8);
  }

  // PV: per chunk O(64n x 64d) = P(64x64) . V(64m x 64d); B from V^T planes
  size_t obase = ((size_t)b * 64 + ch) << 16;
  for (int cd = 0; cd < 16; ++cd) {
    stage_vt(vpl, wv, SBh, SBl, cd, t);
    __syncthreads();
    f4 po[4];
#pragma unroll
    for (int cb = 0; cb < 4; ++cb)
#pragma unroll
      for (int e = 0; e < 4; ++e) po[cb][e] = 0.f;
#pragma unroll
    for (int ks = 0; ks < 2; ++ks) {
      const int ko = ks * 32 + g * 8;
#pragma unroll
      for (int cb = 0; cb < 4; ++cb) {
        short8 bh = ldfrag(SBh, cb * 16 + r16, ko);
        short8 bl = ldfrag(SBl, cb * 16 + r16, ko);
        po[cb] = __builtin_amdgcn_mfma_f32_16x16x32_bf16(pah[ks], bh, po[cb], 0, 0, 0);
        po[cb] = __builtin_amdgcn_mfma_f32_16x16x32_bf16(pah[ks], bl, po[cb], 0, 0, 0);
        po[cb] = __builtin_amdgcn_mfma_f32_16x16x32_bf16(pal[ks], bh, po[cb], 0, 0, 0);
      }
    }
#pragma unroll
    for (int cb = 0; cb < 4; ++cb)
#pragma unroll
      for (int r = 0; r < 4; ++r) {
        int n = wid * 16 + g * 4 + r;
        int d = cd * 64 + cb * 16 + r16;
        int hh = ((d >> 5) << 3) + (n >> 3);
        int ww = ((d & 31) << 3) + (n & 7);
        out[obase + hh * 256 + ww] = po[cb][r];
      }
    __syncthreads();
  }
}

extern "C" void kernel_launch(void* const* d_in, const int* in_sizes, int n_in,
                              void* d_out, int out_size, void* d_ws,
                              size_t ws_size, hipStream_t stream) {
  const float* x = (const float*)d_in[0];
  const float* wqkv = (const float*)d_in[1];
  const float* wdw = (const float*)d_in[2];
  const float* wproj = (const float*)d_in[3];
  const float* temp = (const float*)d_in[4];
  float* out = (float*)d_out;
  float* qkv0 = (float*)d_ws;  // 8*192*65536*4 = 402,653,184 bytes

  k_pwm<192><<<8192, 256, 0, stream>>>(x, wqkv, qkv0);
  k_attn<<<512, 256, 0, stream>>>(qkv0, wdw, temp, out);
  k_pwm<64><<<8192, 256, 0, stream>>>(out, wproj, out);
}

// Round 9
// 403.826 us; speedup vs baseline: 2.0869x; 1.0038x over previous
//
#include <hip/hip_runtime.h>
#include <hip/hip_bf16.h>

// CxNNxNN attention. B=8, C=64, H=W=256, head=8, N=8.
// token n = (h&7)*8 + (w&7)  [64], feature d = (h>>3)*32 + (w>>3)  [1024].

typedef __attribute__((ext_vector_type(8))) short short8;  // 8 bf16 (4 VGPR)
typedef __attribute__((ext_vector_type(4))) float f4;      // MFMA acc
typedef unsigned short u16;

#define PST 72  // bf16 plane row stride (ushorts)

// ---------------- bf16 hi/lo helpers ----------------
__device__ __forceinline__ float tof(u16 u) {
  return __builtin_bit_cast(float, ((unsigned)u) << 16);
}
__device__ __forceinline__ void fsplit(float o, u16& h, u16& l) {
  unsigned u = __builtin_bit_cast(unsigned, o);
  h = (u16)(u >> 16);  // truncate; lo compensates
  float hf = __builtin_bit_cast(float, u & 0xffff0000u);
  l = (u16)(__builtin_bit_cast(unsigned, o - hf) >> 16);
}
__device__ __forceinline__ short8 ldfrag(const u16* p, int row, int ko) {
  return *(const short8*)&p[row * PST + ko];
}

// ---------------- K1/K3: pointwise GEMM on MFMA (validated R8) ----------------
template <int OC>
__global__ __launch_bounds__(256) void k_pwm(const float* in,
                                             const float* __restrict__ w,
                                             float* outp) {
  constexpr int MT = OC / 64;
  __shared__ u16 XTh[64 * PST], XTl[64 * PST];
  const int t = threadIdx.x;
  const int px = t & 63, cg = t >> 6;
  const size_t pix0 = (size_t)blockIdx.x * 64;
  const int b = (int)(pix0 >> 16);
  const int hw0 = (int)(pix0 & 65535);
  const float* ib = in + (((size_t)b * 64) << 16) + hw0 + px;
#pragma unroll
  for (int j = 0; j < 2; ++j) {
    short8 hv, lv;
#pragma unroll
    for (int e = 0; e < 8; ++e) {
      int c = cg * 16 + j * 8 + e;
      float xv = ib[(size_t)c << 16];
      u16 h, l;
      fsplit(xv, h, l);
      hv[e] = (short)h;
      lv[e] = (short)l;
    }
    *(short8*)&XTh[px * PST + cg * 16 + j * 8] = hv;
    *(short8*)&XTl[px * PST + cg * 16 + j * 8] = lv;
  }
  __syncthreads();
  const int wid = t >> 6, g = (t >> 4) & 3, r16 = t & 15;
  const int oc0 = wid * 16 * MT;
  short8 ah[MT][2], al[MT][2];
#pragma unroll
  for (int m = 0; m < MT; ++m)
#pragma unroll
    for (int ks = 0; ks < 2; ++ks) {
      const float* wr = w + (oc0 + m * 16 + r16) * 64 + ks * 32 + g * 8;
      float4 a0 = *(const float4*)wr;
      float4 a1 = *(const float4*)(wr + 4);
      float av[8] = {a0.x, a0.y, a0.z, a0.w, a1.x, a1.y, a1.z, a1.w};
      short8 h8, l8;
#pragma unroll
      for (int e = 0; e < 8; ++e) {
        u16 h, l;
        fsplit(av[e], h, l);
        h8[e] = (short)h;
        l8[e] = (short)l;
      }
      ah[m][ks] = h8;
      al[m][ks] = l8;
    }
  float* ob = outp + (((size_t)b * OC) << 16) + hw0;
#pragma unroll
  for (int nt = 0; nt < 4; ++nt) {
    short8 bh[2], bl[2];
#pragma unroll
    for (int ks = 0; ks < 2; ++ks) {
      bh[ks] = ldfrag(XTh, nt * 16 + r16, ks * 32 + g * 8);
      bl[ks] = ldfrag(XTl, nt * 16 + r16, ks * 32 + g * 8);
    }
    f4 acc[MT];
#pragma unroll
    for (int m = 0; m < MT; ++m)
#pragma unroll
      for (int e = 0; e < 4; ++e) acc[m][e] = 0.f;
#pragma unroll
    for (int m = 0; m < MT; ++m)
#pragma unroll
      for (int ks = 0; ks < 2; ++ks) {
        acc[m] = __builtin_amdgcn_mfma_f32_16x16x32_bf16(ah[m][ks], bh[ks], acc[m], 0, 0, 0);
        acc[m] = __builtin_amdgcn_mfma_f32_16x16x32_bf16(ah[m][ks], bl[ks], acc[m], 0, 0, 0);
        acc[m] = __builtin_amdgcn_mfma_f32_16x16x32_bf16(al[m][ks], bh[ks], acc[m], 0, 0, 0);
      }
#pragma unroll
    for (int m = 0; m < MT; ++m)
#pragma unroll
      for (int e = 0; e < 4; ++e) {
        int oc = oc0 + m * 16 + g * 4 + e;
        ob[((size_t)oc << 16) + nt * 16 + r16] = acc[m][e];
      }
  }
}

// ---- depthwise 3x3 conv: one run = 8 tokens (n=nb..nb+7) at one feature dcol --
__device__ __forceinline__ void conv_run(const float* __restrict__ pl,
                                         const float* __restrict__ w9, int cd,
                                         int r, float o[8], int& nb,
                                         int& dcol) {
  int lr = r >> 5, w0 = r & 31;
  int h = cd * 16 + lr;
  float rv[3][10];
#pragma unroll
  for (int dy = 0; dy < 3; ++dy) {
    int hy = h + dy - 1;
    bool hv = (hy >= 0) && (hy < 256);
#pragma unroll
    for (int j = 0; j < 10; ++j) rv[dy][j] = 0.f;
    if (hv) {
      const float* rp = pl + hy * 256;
      const float4* rp4 = (const float4*)(rp + w0 * 8);
      float4 a = rp4[0], b4 = rp4[1];
      rv[dy][1] = a.x;  rv[dy][2] = a.y;  rv[dy][3] = a.z;  rv[dy][4] = a.w;
      rv[dy][5] = b4.x; rv[dy][6] = b4.y; rv[dy][7] = b4.z; rv[dy][8] = b4.w;
      rv[dy][0] = (w0 > 0) ? rp[w0 * 8 - 1] : 0.f;
      rv[dy][9] = (w0 < 31) ? rp[w0 * 8 + 8] : 0.f;
    }
  }
  nb = (lr & 7) * 8;
  dcol = ((lr >> 3) << 5) + w0;
#pragma unroll
  for (int i = 0; i < 8; ++i) {
    o[i] = fmaf(w9[0], rv[0][i], fmaf(w9[1], rv[0][i + 1], fmaf(w9[2], rv[0][i + 2],
            fmaf(w9[3], rv[1][i], fmaf(w9[4], rv[1][i + 1], fmaf(w9[5], rv[1][i + 2],
            fmaf(w9[6], rv[2][i], fmaf(w9[7], rv[2][i + 1], w9[8] * rv[2][i + 2]))))))));
  }
}

// stage Q/K chunk as hi/lo planes [64 n][PST d]
__device__ __forceinline__ void stage_nk(const float* __restrict__ pl,
                                         const float* __restrict__ w9,
                                         u16* __restrict__ ph,
                                         u16* __restrict__ plo, int cd, int t) {
#pragma unroll
  for (int rr = 0; rr < 2; ++rr) {
    float o[8]; int nb, dcol;
    conv_run(pl, w9, cd, t + rr * 256, o, nb, dcol);
#pragma unroll
    for (int i = 0; i < 8; ++i) {
      u16 h, l;
      fsplit(o[i], h, l);
      ph[(nb + i) * PST + dcol] = h;
      plo[(nb + i) * PST + dcol] = l;
    }
  }
}

// stage V chunk TRANSPOSED [64 d][PST n]: packed b128 writes
__device__ __forceinline__ void stage_vt(const float* __restrict__ pl,
                                         const float* __restrict__ w9,
                                         u16* __restrict__ ph,
                                         u16* __restrict__ plo, int cd, int t) {
#pragma unroll
  for (int rr = 0; rr < 2; ++rr) {
    float o[8]; int nb, dcol;
    conv_run(pl, w9, cd, t + rr * 256, o, nb, dcol);
    short8 hv, lv;
#pragma unroll
    for (int i = 0; i < 8; ++i) {
      u16 h, l;
      fsplit(o[i], h, l);
      hv[i] = (short)h;
      lv[i] = (short)l;
    }
    *(short8*)&ph[dcol * PST + nb] = hv;
    *(short8*)&plo[dcol * PST + nb] = lv;
  }
}

// ---------------- K2a: QK^T partial over a d-half ----------------
// R8: k_attn 233us @ 22.7% occ -- grid 512 = 2 blocks/CU was the limiter.
// Split: block (u, hd) accumulates S-partial + sumsq-partial over chunks
// hd*8..hd*8+7, stashing raw results INSIDE the dead space of this unit's
// Q plane at qpl + hd*32768 + 256 (offset 256 clears cross-half conv halo:
// (u,1) reads row 127 = last 256 floats of half0; (u,0) reads row 128 =
// first 256 of half1; each block writes only after its own reads).
__global__ __launch_bounds__(256) void k_qkt(float* qkv0,
                                             const float* __restrict__ wdw) {
  __shared__ u16 SAh[64 * PST], SAl[64 * PST];
  __shared__ u16 SBh[64 * PST], SBl[64 * PST];
  __shared__ float red[64 * 8];
  const int t = threadIdx.x;
  const int u = blockIdx.x >> 1, hd = blockIdx.x & 1;
  const int b = u >> 6, ch = u & 63;
  float* qpl = qkv0 + (((size_t)b * 192 + ch) << 16);
  const float* kpl = qkv0 + (((size_t)b * 192 + 64 + ch) << 16);
  float wq[9], wk[9];
#pragma unroll
  for (int i = 0; i < 9; ++i) {
    wq[i] = wdw[ch * 9 + i];
    wk[i] = wdw[(64 + ch) * 9 + i];
  }
  const int wid = t >> 6, g = (t >> 4) & 3, r16 = t & 15;
  f4 acc[4];
#pragma unroll
  for (int cb = 0; cb < 4; ++cb)
#pragma unroll
    for (int e = 0; e < 4; ++e) acc[cb][e] = 0.f;
  float sqQ = 0.f, sqK = 0.f;

  for (int c8 = 0; c8 < 8; ++c8) {
    const int cd = hd * 8 + c8;
    stage_nk(qpl, wq, SAh, SAl, cd, t);
    stage_nk(kpl, wk, SBh, SBl, cd, t);
    __syncthreads();
    {  // sumsq partials (hi+lo reconstructed): row n=t>>2, 16 cols
      const int n = t >> 2, c0 = (t & 3) << 4;
#pragma unroll
      for (int h2 = 0; h2 < 2; ++h2) {
        short8 qh = *(const short8*)&SAh[n * PST + c0 + 8 * h2];
        short8 ql = *(const short8*)&SAl[n * PST + c0 + 8 * h2];
        short8 kh = *(const short8*)&SBh[n * PST + c0 + 8 * h2];
        short8 kl = *(const short8*)&SBl[n * PST + c0 + 8 * h2];
#pragma unroll
        for (int e = 0; e < 8; ++e) {
          float qv = tof((u16)qh[e]) + tof((u16)ql[e]);
          float kv = tof((u16)kh[e]) + tof((u16)kl[e]);
          sqQ = fmaf(qv, qv, sqQ);
          sqK = fmaf(kv, kv, sqK);
        }
      }
    }
#pragma unroll
    for (int ks = 0; ks < 2; ++ks) {
      const int ko = ks * 32 + g * 8;
      short8 ah = ldfrag(SAh, wid * 16 + r16, ko);
      short8 al = ldfrag(SAl, wid * 16 + r16, ko);
#pragma unroll
      for (int cb = 0; cb < 4; ++cb) {
        short8 bh = ldfrag(SBh, cb * 16 + r16, ko);
        short8 bl = ldfrag(SBl, cb * 16 + r16, ko);
        acc[cb] = __builtin_amdgcn_mfma_f32_16x16x32_bf16(ah, bh, acc[cb], 0, 0, 0);
        acc[cb] = __builtin_amdgcn_mfma_f32_16x16x32_bf16(ah, bl, acc[cb], 0, 0, 0);
        acc[cb] = __builtin_amdgcn_mfma_f32_16x16x32_bf16(al, bh, acc[cb], 0, 0, 0);
      }
    }
    __syncthreads();
  }

  // reduce sumsq partials across 4 col-groups
  red[(t >> 2) * 8 + (t & 3)] = sqQ;
  red[(t >> 2) * 8 + 4 + (t & 3)] = sqK;
  __syncthreads();
  float* stash = qpl + hd * 32768 + 256;  // S[4096] then sumsq[128]
  if (t < 128) {
    int n = t & 63;
    int o = (t >> 6) * 4;
    float s = red[n * 8 + o] + red[n * 8 + o + 1] + red[n * 8 + o + 2] +
              red[n * 8 + o + 3];
    stash[4096 + (t >> 6) * 64 + n] = s;  // 0..63 = Q, 64..127 = K
  }
  // raw S partial: (n = 16*wid+4*g+r, m = 16*cb+r16) -> 64B runs
#pragma unroll
  for (int cb = 0; cb < 4; ++cb)
#pragma unroll
    for (int r = 0; r < 4; ++r) {
      int n = wid * 16 + g * 4 + r, m = cb * 16 + r16;
      stash[n * 64 + m] = acc[cb][r];
    }
}

// ---------------- K2b: softmax + PV over a d-half ----------------
__global__ __launch_bounds__(256) void k_pv(const float* qkv0,
                                            const float* __restrict__ wdw,
                                            const float* __restrict__ temperature,
                                            float* __restrict__ out) {
  __shared__ u16 Ph[64 * PST], Pl[64 * PST];
  __shared__ u16 Vh[64 * PST], Vl[64 * PST];
  __shared__ float invk[64];
  const int t = threadIdx.x;
  const int u = blockIdx.x >> 1, hd = blockIdx.x & 1;
  const int b = u >> 6, ch = u & 63;
  const float* vpl = qkv0 + (((size_t)b * 192 + 128 + ch) << 16);
  const float* sb0 = qkv0 + (((size_t)b * 192 + ch) << 16) + 256;
  const float* sb1 = sb0 + 32768;
  float wv[9];
#pragma unroll
  for (int i = 0; i < 9; ++i) wv[i] = wdw[(128 + ch) * 9 + i];
  const float tscale = temperature[ch >> 3];
  const int wid = t >> 6, g = (t >> 4) & 3, r16 = t & 15;

  if (t < 64) {
    float s = sb0[4096 + 64 + t] + sb1[4096 + 64 + t];
    invk[t] = 1.f / fmaxf(sqrtf(s), 1e-12f);
  }
  __syncthreads();

  // softmax: lane group (wid, r16) owns row = 16*wid + r16; quarter g = 16 m
  const int row = wid * 16 + r16;
  float sq = sb0[4096 + row] + sb1[4096 + row];
  const float invq = 1.f / fmaxf(sqrtf(sq), 1e-12f);
  float sv[16];
  const float* s0r = sb0 + row * 64 + g * 16;
  const float* s1r = sb1 + row * 64 + g * 16;
  float mx = -1e30f;
#pragma unroll
  for (int j = 0; j < 16; ++j) {
    sv[j] = (s0r[j] + s1r[j]) * invq * invk[g * 16 + j] * tscale;
    mx = fmaxf(mx, sv[j]);
  }
  mx = fmaxf(mx, __shfl_xor(mx, 16));
  mx = fmaxf(mx, __shfl_xor(mx, 32));
  float ss = 0.f;
#pragma unroll
  for (int j = 0; j < 16; ++j) {
    sv[j] = __expf(sv[j] - mx);
    ss += sv[j];
  }
  ss += __shfl_xor(ss, 16);
  ss += __shfl_xor(ss, 32);
  const float rs = 1.f / ss;
  short8 h0, h1, l0, l1;
#pragma unroll
  for (int j = 0; j < 8; ++j) {
    u16 h, l;
    fsplit(sv[j] * rs, h, l);
    h0[j] = (short)h; l0[j] = (short)l;
    fsplit(sv[8 + j] * rs, h, l);
    h1[j] = (short)h; l1[j] = (short)l;
  }
  *(short8*)&Ph[row * PST + g * 16] = h0;
  *(short8*)&Ph[row * PST + g * 16 + 8] = h1;
  *(short8*)&Pl[row * PST + g * 16] = l0;
  *(short8*)&Pl[row * PST + g * 16 + 8] = l1;
  __syncthreads();

  short8 pah[2], pal[2];
#pragma unroll
  for (int ks = 0; ks < 2; ++ks) {
    pah[ks] = ldfrag(Ph, wid * 16 + r16, ks * 32 + g * 8);
    pal[ks] = ldfrag(Pl, wid * 16 + r16, ks * 32 + g * 8);
  }

  size_t obase = ((size_t)b * 64 + ch) << 16;
  for (int c8 = 0; c8 < 8; ++c8) {
    const int cd = hd * 8 + c8;
    stage_vt(vpl, wv, Vh, Vl, cd, t);
    __syncthreads();
    f4 po[4];
#pragma unroll
    for (int cb = 0; cb < 4; ++cb)
#pragma unroll
      for (int e = 0; e < 4; ++e) po[cb][e] = 0.f;
#pragma unroll
    for (int ks = 0; ks < 2; ++ks) {
      const int ko = ks * 32 + g * 8;
#pragma unroll
      for (int cb = 0; cb < 4; ++cb) {
        short8 bh = ldfrag(Vh, cb * 16 + r16, ko);
        short8 bl = ldfrag(Vl, cb * 16 + r16, ko);
        po[cb] = __builtin_amdgcn_mfma_f32_16x16x32_bf16(pah[ks], bh, po[cb], 0, 0, 0);
        po[cb] = __builtin_amdgcn_mfma_f32_16x16x32_bf16(pah[ks], bl, po[cb], 0, 0, 0);
        po[cb] = __builtin_amdgcn_mfma_f32_16x16x32_bf16(pal[ks], bh, po[cb], 0, 0, 0);
      }
    }
#pragma unroll
    for (int cb = 0; cb < 4; ++cb)
#pragma unroll
      for (int r = 0; r < 4; ++r) {
        int n = wid * 16 + g * 4 + r;
        int d = cd * 64 + cb * 16 + r16;
        int hh = ((d >> 5) << 3) + (n >> 3);
        int ww = ((d & 31) << 3) + (n & 7);
        out[obase + hh * 256 + ww] = po[cb][r];
      }
    __syncthreads();
  }
}

extern "C" void kernel_launch(void* const* d_in, const int* in_sizes, int n_in,
                              void* d_out, int out_size, void* d_ws,
                              size_t ws_size, hipStream_t stream) {
  const float* x = (const float*)d_in[0];
  const float* wqkv = (const float*)d_in[1];
  const float* wdw = (const float*)d_in[2];
  const float* wproj = (const float*)d_in[3];
  const float* temp = (const float*)d_in[4];
  float* out = (float*)d_out;
  float* qkv0 = (float*)d_ws;  // 402,653,184 bytes (S/sumsq stash inside)

  k_pwm<192><<<8192, 256, 0, stream>>>(x, wqkv, qkv0);
  k_qkt<<<1024, 256, 0, stream>>>(qkv0, wdw);
  k_pv<<<1024, 256, 0, stream>>>(qkv0, wdw, temp, out);
  k_pwm<64><<<8192, 256, 0, stream>>>(out, wproj, out);
}